// Round 7
// baseline (723.744 us; speedup 1.0000x reference)
//
#include <hip/hip_runtime.h>

typedef __attribute__((ext_vector_type(8))) short short8;
typedef __attribute__((ext_vector_type(4))) float f32x4;

#if __has_builtin(__builtin_amdgcn_exp2f)
#define EXP2F(x) __builtin_amdgcn_exp2f(x)
#else
#define EXP2F(x) exp2f(x)
#endif
#if __has_builtin(__builtin_amdgcn_rcpf)
#define RCPF(x) __builtin_amdgcn_rcpf(x)
#else
#define RCPF(x) (1.0f/(x))
#endif

#define SQ 208   // q/k/o row stride (96 bf16 cols + pad, 16B aligned)
#define SV 144   // vT row stride (64 bf16 cols + pad, 16B aligned)

// LDS (bytes):
//   x_lds [64][400] @0..25600   (staging; dead after bx preload)
//   q_lds [64][208] @0      13312  (overlays x region after barrier)
//   k_lds [64][208] @13312  13312
//   v_lds [96][144] @26624  13824  (vT per 3-head group: row = hl*32+d, col = t)
//   o_lds [64][208] @40448  13312
// total 53760 -> 3 blocks/CU IF total regs (VGPR+AGPR) <= 128
#define LDS_TOTAL 53760

__device__ __forceinline__ unsigned short f2bf(float f) {
    union { float f; unsigned u; } v; v.f = f;
    unsigned r = v.u + 0x7FFFu + ((v.u >> 16) & 1u);
    return (unsigned short)(r >> 16);
}
__device__ __forceinline__ unsigned pkbf(float lo, float hi) {
    return (unsigned)f2bf(lo) | ((unsigned)f2bf(hi) << 16);
}

__global__ void cvt_weights(const float* __restrict__ qw, const float* __restrict__ hw,
                            unsigned short* __restrict__ wq, unsigned short* __restrict__ wh) {
    int i = blockIdx.x * 256 + threadIdx.x;
    if (i < 576 * 192) wq[i] = f2bf(qw[i]);
    if (i < 192 * 192) wh[i] = f2bf(hw[i]);
}

// Register budget: occupancy quantizes at total (VGPR+AGPR) = 64/128/256 (m69).
// R6: bx[4][6]=96 + acc=48 -> total ~164 -> 256-bucket -> 2 blocks/CU.
// Here: bx[2][6]=48 (token-pair per wave), bx/acc lifetimes split by a barrier
// (qkv1 before proj0, acc born via C=0 mfma), bo read per-kt (16 regs).
// Peak live ~110 -> (256,4) budget 128, no spill expected.
__global__ __launch_bounds__(256, 4) void wmha(
    const float* __restrict__ x, const float* __restrict__ qkv_b,
    const float* __restrict__ head_b, const unsigned short* __restrict__ wq,
    const unsigned short* __restrict__ whc, float* __restrict__ out)
{
    extern __shared__ char smem[];
    char* const x_lds = smem;
    char* const q_lds = smem;
    char* const k_lds = smem + 13312;
    char* const v_lds = smem + 26624;
    char* const o_lds = smem + 40448;

    const int tid = threadIdx.x;
    const int ln  = tid & 15;
    const int hi4 = (tid >> 4) & 3;
    const int wid = tid >> 6;

    const int bid  = blockIdx.x;
    const int widx = (bid & 7) * 1152 + (bid >> 3);   // bijective XCD swizzle (9216 % 8 == 0)
    const int b  = widx / 2304;
    const int rr = widx % 2304;
    const int oy = rr / 48, ox = rr % 48;
    const int row0 = oy * 8, col0 = ox * 8;

    // ---- stage x window -> x_lds bf16 [t][c], stride 400 ----
    {
        const int tok = tid & 63;
        const int qd  = tid >> 6;
        const int y = tok >> 3, xx = tok & 7;
        const float* gp = x + ((size_t)(b * 192) * 384 + (row0 + y)) * 384 + (col0 + xx);
        char* wp = x_lds + tok * 400 + qd * 96;
        #pragma unroll
        for (int kk = 0; kk < 12; ++kk) {
            const int c = qd * 48 + kk * 4;
            float f0 = gp[(size_t)(c + 0) * 147456];
            float f1 = gp[(size_t)(c + 1) * 147456];
            float f2 = gp[(size_t)(c + 2) * 147456];
            float f3 = gp[(size_t)(c + 3) * 147456];
            uint2 u;
            u.x = pkbf(f0, f1);
            u.y = pkbf(f2, f3);
            *(uint2*)(wp + kk * 8) = u;
        }
    }
    __syncthreads();

    // wave pins ONLY its token pair p = wid&1 (tiles 2p, 2p+1): 48 VGPR
    const int p = wid & 1;          // token-pair id
    const int eg = wid >> 1;        // e-group: this wave's m-tile parity
    short8 bx[2][6];
    #pragma unroll
    for (int j = 0; j < 2; ++j)
        #pragma unroll
        for (int kt = 0; kt < 6; ++kt)
            bx[j][kt] = *(const short8*)(x_lds + ((2 * p + j) * 16 + ln) * 400 + kt * 64 + hi4 * 16);
    __syncthreads();   // x reads done; q/k may overwrite

    f32x4 acc[3][4];   // defined in proj(0) via C=0 mfma; dead until then

    const float SC2 = 0.25503417f;  // (1/sqrt(32)) * log2(e)

    // ---- QKV group g: 18 m-tiles; wave covers 9 tiles of parity eg, tokens 2p..2p+1 ----
    auto qkv = [&](int g) {
        for (int mt = eg; mt < 18; mt += 2) {
            const int hl = mt / 6, sec = (mt % 6) >> 1, e = mt & 1;   // e == eg
            const int r0 = sec * 192 + (3 * g + hl) * 32 + e * 16;
            short8 wf[6];
            #pragma unroll
            for (int kt = 0; kt < 6; ++kt)
                wf[kt] = *(const short8*)(wq + (r0 + ln) * 192 + kt * 32 + hi4 * 8);
            if (sec < 2) {
                // D[d][t] = W x^T -> packed [t][d] store
                char* dst = (sec == 0) ? q_lds : k_lds;
                const float4 bias = *(const float4*)(qkv_b + r0 + hi4 * 4);
                #pragma unroll
                for (int j = 0; j < 2; ++j) {
                    const int nt = 2 * p + j;
                    f32x4 a = {0.f, 0.f, 0.f, 0.f};
                    #pragma unroll
                    for (int kt = 0; kt < 6; ++kt)
                        a = __builtin_amdgcn_mfma_f32_16x16x32_bf16(wf[kt], bx[j][kt], a, 0, 0, 0);
                    uint2 u;
                    u.x = pkbf(a[0] + bias.x, a[1] + bias.y);
                    u.y = pkbf(a[2] + bias.z, a[3] + bias.w);
                    *(uint2*)(dst + (nt * 16 + ln) * SQ + hl * 64 + (e * 16 + hi4 * 4) * 2) = u;
                }
            } else {
                // swapped: D[t][d] = x W^T -> packed vT[d][t] store
                const float bv = qkv_b[r0 + ln];
                #pragma unroll
                for (int j = 0; j < 2; ++j) {
                    const int nt = 2 * p + j;
                    f32x4 a = {0.f, 0.f, 0.f, 0.f};
                    #pragma unroll
                    for (int kt = 0; kt < 6; ++kt)
                        a = __builtin_amdgcn_mfma_f32_16x16x32_bf16(bx[j][kt], wf[kt], a, 0, 0, 0);
                    uint2 u;
                    u.x = pkbf(a[0] + bv, a[1] + bv);
                    u.y = pkbf(a[2] + bv, a[3] + bv);
                    *(uint2*)(v_lds + (hl * 32 + e * 16 + ln) * SV + (nt * 16 + hi4 * 4) * 2) = u;
                }
            }
        }
    };

    // ---- attention: 12 units (3 heads x 4 i-tiles) / 4 waves; P kept in registers ----
    auto attn = [&](int g) {
        #pragma unroll
        for (int uu = 0; uu < 3; ++uu) {
            const int u = wid + uu * 4;
            const int hl = u >> 2, i0 = (u & 3) * 16;
            const short8 bq = *(const short8*)(q_lds + (i0 + ln) * SQ + hl * 64 + hi4 * 16);
            f32x4 s[4];
            #pragma unroll
            for (int kt = 0; kt < 4; ++kt) {
                const short8 ak = *(const short8*)(k_lds + (kt * 16 + ln) * SQ + hl * 64 + hi4 * 16);
                f32x4 z = {0.f, 0.f, 0.f, 0.f};
                s[kt] = __builtin_amdgcn_mfma_f32_16x16x32_bf16(ak, bq, z, 0, 0, 0);
            }
            // lane (ln, h=hi4) holds S[k = kt*16+h*4+r][i = i0+ln]
            float m = s[0][0];
            #pragma unroll
            for (int kt = 0; kt < 4; ++kt)
                #pragma unroll
                for (int r = 0; r < 4; ++r) m = fmaxf(m, s[kt][r]);
            m = fmaxf(m, __shfl_xor(m, 16));
            m = fmaxf(m, __shfl_xor(m, 32));
            float sum = 0.f;
            #pragma unroll
            for (int kt = 0; kt < 4; ++kt)
                #pragma unroll
                for (int r = 0; r < 4; ++r) {
                    s[kt][r] = EXP2F((s[kt][r] - m) * SC2);
                    sum += s[kt][r];
                }
            sum += __shfl_xor(sum, 16);
            sum += __shfl_xor(sum, 32);
            const float rinv = RCPF(sum);
            unsigned pk[4][2];
            #pragma unroll
            for (int kt = 0; kt < 4; ++kt) {
                pk[kt][0] = pkbf(s[kt][0] * rinv, s[kt][1] * rinv);
                pk[kt][1] = pkbf(s[kt][2] * rinv, s[kt][3] * rinv);
            }
            // redistribute to PV B-frag layout: lane needs P[k'=kc*32+h*8+j][i], j=0..7
            const int h = hi4;
            const bool hiH = (h >= 2);
            short8 pf[2];
            #pragma unroll
            for (int kc = 0; kc < 2; ++kc) {
                unsigned w[4];
                #pragma unroll
                for (int rp = 0; rp < 2; ++rp) {
                    const unsigned pkE = pk[2 * kc][rp], pkO = pk[2 * kc + 1][rp];
                    unsigned r16 = __shfl_xor(hiH ? pkO : pkE, 16);
                    unsigned r32 = __shfl_xor(hiH ? pkE : pkO, 32);
                    unsigned r48 = __shfl_xor(hiH ? pkE : pkO, 48);
                    unsigned ev = (h == 0) ? pkE : (h == 1) ? r48 : (h == 2) ? r32 : r16;
                    unsigned od = (h == 3) ? pkO : (h == 0) ? r16 : (h == 1) ? r32 : r48;
                    w[rp] = ev; w[2 + rp] = od;
                }
                union { uint4 u4; short8 s8; } cv;
                cv.u4.x = w[0]; cv.u4.y = w[1]; cv.u4.z = w[2]; cv.u4.w = w[3];
                pf[kc] = cv.s8;
            }
            // PV swapped: D[d][i] = vT P^T
            #pragma unroll
            for (int dt = 0; dt < 2; ++dt) {
                f32x4 o = {0.f, 0.f, 0.f, 0.f};
                #pragma unroll
                for (int kc = 0; kc < 2; ++kc) {
                    const short8 av = *(const short8*)(v_lds + (hl * 32 + dt * 16 + ln) * SV + kc * 64 + hi4 * 16);
                    o = __builtin_amdgcn_mfma_f32_16x16x32_bf16(av, pf[kc], o, 0, 0, 0);
                }
                uint2 u2;
                u2.x = pkbf(o[0], o[1]);
                u2.y = pkbf(o[2], o[3]);
                *(uint2*)(o_lds + (i0 + ln) * SQ + hl * 64 + (dt * 16 + hi4 * 4) * 2) = u2;
            }
        }
    };

    // ---- head-proj partial for group g; acc born at g==0,kt==0 via C=0 mfma ----
    auto proj = [&](int g) {
        #pragma unroll
        for (int kt = 0; kt < 3; ++kt) {
            short8 bo[4];
            #pragma unroll
            for (int nt = 0; nt < 4; ++nt)
                bo[nt] = *(const short8*)(o_lds + (nt * 16 + ln) * SQ + kt * 64 + hi4 * 16);
            #pragma unroll
            for (int mm = 0; mm < 3; ++mm) {
                const int c0 = (wid * 3 + mm) * 16;
                const short8 af = *(const short8*)(whc + (c0 + ln) * 192 + g * 96 + kt * 32 + hi4 * 8);
                #pragma unroll
                for (int nt = 0; nt < 4; ++nt) {
                    f32x4 cin = (g == 0 && kt == 0) ? (f32x4){0.f, 0.f, 0.f, 0.f} : acc[mm][nt];
                    acc[mm][nt] = __builtin_amdgcn_mfma_f32_16x16x32_bf16(af, bo[nt], cin, 0, 0, 0);
                }
            }
        }
    };

    qkv(0);
    __syncthreads();
    attn(0);
    __syncthreads();
    qkv(1);            // bx last use; overwrites q/k/v (group 0 consumed); o_lds(0) intact
    __syncthreads();   // splits bx / acc live ranges
    proj(0);           // acc born here (bx dead -> registers reusable)
    __syncthreads();   // proj0 o-reads complete before attn1 overwrites o_lds
    attn(1);
    __syncthreads();
    proj(1);

    // ---- final store: out[c][spatial t] = acc + head_b ----
    #pragma unroll
    for (int mm = 0; mm < 3; ++mm) {
        const int c0 = (wid * 3 + mm) * 16;
        const float4 hb = *(const float4*)(head_b + c0 + hi4 * 4);
        #pragma unroll
        for (int nt = 0; nt < 4; ++nt) {
            const int tt = nt * 16 + ln;
            const int y = tt >> 3, xx = tt & 7;
            float* op = out + ((size_t)(b * 192) * 384 + (row0 + y)) * 384 + (col0 + xx);
            op[(size_t)(c0 + hi4 * 4 + 0) * 147456] = acc[mm][nt][0] + hb.x;
            op[(size_t)(c0 + hi4 * 4 + 1) * 147456] = acc[mm][nt][1] + hb.y;
            op[(size_t)(c0 + hi4 * 4 + 2) * 147456] = acc[mm][nt][2] + hb.z;
            op[(size_t)(c0 + hi4 * 4 + 3) * 147456] = acc[mm][nt][3] + hb.w;
        }
    }
}

extern "C" void kernel_launch(void* const* d_in, const int* in_sizes, int n_in,
                              void* d_out, int out_size, void* d_ws, size_t ws_size,
                              hipStream_t stream) {
    const float* x      = (const float*)d_in[0];
    const float* qkv_w  = (const float*)d_in[1];
    const float* qkv_b  = (const float*)d_in[2];
    const float* head_w = (const float*)d_in[3];
    const float* head_b = (const float*)d_in[4];
    float* out = (float*)d_out;

    unsigned short* wq  = (unsigned short*)d_ws;   // 576*192 ushort
    unsigned short* whc = wq + 576 * 192;          // 192*192 ushort

    cvt_weights<<<432, 256, 0, stream>>>(qkv_w, head_w, wq, whc);

    wmha<<<9216, 256, LDS_TOTAL, stream>>>(x, qkv_b, head_b, wq, whc, out);
}

// Round 8
// 560.184 us; speedup vs baseline: 1.2920x; 1.2920x over previous
//
#include <hip/hip_runtime.h>
#include <hip/hip_bf16.h>

typedef __attribute__((ext_vector_type(8))) short short8;
typedef __attribute__((ext_vector_type(4))) float f32x4;

#if __has_builtin(__builtin_amdgcn_exp2f)
#define EXP2F(x) __builtin_amdgcn_exp2f(x)
#else
#define EXP2F(x) exp2f(x)
#endif
#if __has_builtin(__builtin_amdgcn_rcpf)
#define RCPF(x) __builtin_amdgcn_rcpf(x)
#else
#define RCPF(x) (1.0f/(x))
#endif

#define SQ 208   // q/k/o row stride (96 bf16 cols + pad, 16B aligned)
#define SV 144   // vT / p row stride (64 bf16 cols + pad, 16B aligned)

// LDS (bytes) — R4 layout (best measured: 620 us):
//   x_lds [64][400] @0..25600   (staging; dead after bx preload)
//   q_lds [64][208] @0      13312  (overlays x region after barrier)
//   k_lds [64][208] @13312  13312
//   v_lds [96][144] @26624  13824  (vT per 3-head group: row = hl*32+d, col = t)
//   o_lds [64][208] @40448  13312
//   p_scr [4][16][144] @53760 9216 (per-wave private)
#define LDS_TOTAL 62976

__device__ __forceinline__ unsigned short f2bf(float f) {
    union { float f; unsigned u; } v; v.f = f;
    unsigned r = v.u + 0x7FFFu + ((v.u >> 16) & 1u);
    return (unsigned short)(r >> 16);
}
// packed f32x2 -> bf16x2 via compiler (emits v_cvt_pk_bf16_f32); lo -> bits[15:0]
__device__ __forceinline__ unsigned pk2(float lo, float hi) {
    __hip_bfloat162 h = __float22bfloat162_rn(make_float2(lo, hi));
    union { __hip_bfloat162 h; unsigned u; } cv;
    cv.h = h;
    return cv.u;
}

__global__ void cvt_weights(const float* __restrict__ qw, const float* __restrict__ hw,
                            unsigned short* __restrict__ wq, unsigned short* __restrict__ wh) {
    int i = blockIdx.x * 256 + threadIdx.x;
    if (i < 576 * 192) wq[i] = f2bf(qw[i]);
    if (i < 192 * 192) wh[i] = f2bf(hw[i]);
}

// (256,2): proven spill-free (R4: 116 VGPR). Occupancy 2 blocks/CU; R7 proved
// 3 blocks/CU costs more ILP than it gains -> stay at fat-phase structure.
__global__ __launch_bounds__(256, 2) void wmha(
    const float* __restrict__ x, const float* __restrict__ qkv_b,
    const float* __restrict__ head_b, const unsigned short* __restrict__ wq,
    const unsigned short* __restrict__ whc, float* __restrict__ out)
{
    extern __shared__ char smem[];
    char* const x_lds = smem;
    char* const q_lds = smem;
    char* const k_lds = smem + 13312;
    char* const v_lds = smem + 26624;
    char* const o_lds = smem + 40448;

    const int tid = threadIdx.x;
    const int ln  = tid & 15;
    const int hi4 = (tid >> 4) & 3;
    const int wid = tid >> 6;
    char* const p_scr = smem + 53760 + wid * 2304;

    const int bid  = blockIdx.x;
    const int widx = (bid & 7) * 1152 + (bid >> 3);   // bijective XCD swizzle (9216 % 8 == 0)
    const int b  = widx / 2304;
    const int rr = widx % 2304;
    const int oy = rr / 48, ox = rr % 48;
    const int row0 = oy * 8, col0 = ox * 8;

    // ---- stage x window -> x_lds bf16 [t][c], stride 400 ----
    {
        const int tok = tid & 63;
        const int qd  = tid >> 6;
        const int y = tok >> 3, xx = tok & 7;
        const float* gp = x + ((size_t)(b * 192) * 384 + (row0 + y)) * 384 + (col0 + xx);
        char* wp = x_lds + tok * 400 + qd * 96;
        #pragma unroll
        for (int kk = 0; kk < 12; ++kk) {
            const int c = qd * 48 + kk * 4;
            float f0 = gp[(size_t)(c + 0) * 147456];
            float f1 = gp[(size_t)(c + 1) * 147456];
            float f2 = gp[(size_t)(c + 2) * 147456];
            float f3 = gp[(size_t)(c + 3) * 147456];
            uint2 u;
            u.x = pk2(f0, f1);
            u.y = pk2(f2, f3);
            *(uint2*)(wp + kk * 8) = u;
        }
    }
    __syncthreads();

    // every wave preloads ALL 4 token-tiles' B-frags (96 VGPR); x_lds dead after
    short8 bx[4][6];
    #pragma unroll
    for (int nt = 0; nt < 4; ++nt)
        #pragma unroll
        for (int kt = 0; kt < 6; ++kt)
            bx[nt][kt] = *(const short8*)(x_lds + (nt * 16 + ln) * 400 + kt * 64 + hi4 * 16);
    __syncthreads();   // x reads done; q/k may overwrite

    // head-proj accumulators (register, never materialized in LDS)
    f32x4 acc[3][4];
    #pragma unroll
    for (int mm = 0; mm < 3; ++mm)
        #pragma unroll
        for (int nt = 0; nt < 4; ++nt)
            acc[mm][nt] = (f32x4){0.f, 0.f, 0.f, 0.f};

    const float SC2 = 0.25503417f;  // (1/sqrt(32)) * log2(e)

    // ---- QKV for 3-head group g: 18 m-tiles split across waves (weights read once/block) ----
    // bias folded into MFMA C-init (D = A*B + C with C = bias fragment)
    auto qkv = [&](int g) {
        for (int mt = wid; mt < 18; mt += 4) {
            const int hl = mt / 6, sec = (mt % 6) >> 1, e = mt & 1;
            const int r0 = sec * 192 + (3 * g + hl) * 32 + e * 16;
            short8 wf[6];
            #pragma unroll
            for (int kt = 0; kt < 6; ++kt)
                wf[kt] = *(const short8*)(wq + (r0 + ln) * 192 + kt * 32 + hi4 * 8);
            if (sec < 2) {
                // D[d][t] = W x^T + bias : rows d = hi4*4+r -> bias[r]
                char* dst = (sec == 0) ? q_lds : k_lds;
                const float4 bias = *(const float4*)(qkv_b + r0 + hi4 * 4);
                #pragma unroll
                for (int nt = 0; nt < 4; ++nt) {
                    f32x4 a = {bias.x, bias.y, bias.z, bias.w};
                    #pragma unroll
                    for (int kt = 0; kt < 6; ++kt)
                        a = __builtin_amdgcn_mfma_f32_16x16x32_bf16(wf[kt], bx[nt][kt], a, 0, 0, 0);
                    uint2 u;
                    u.x = pk2(a[0], a[1]);
                    u.y = pk2(a[2], a[3]);
                    *(uint2*)(dst + (nt * 16 + ln) * SQ + hl * 64 + (e * 16 + hi4 * 4) * 2) = u;
                }
            } else {
                // swapped: D[t][d] = x W^T + bias : col d = ln -> bias bv (lane scalar)
                const float bv = qkv_b[r0 + ln];
                #pragma unroll
                for (int nt = 0; nt < 4; ++nt) {
                    f32x4 a = {bv, bv, bv, bv};
                    #pragma unroll
                    for (int kt = 0; kt < 6; ++kt)
                        a = __builtin_amdgcn_mfma_f32_16x16x32_bf16(bx[nt][kt], wf[kt], a, 0, 0, 0);
                    uint2 u;
                    u.x = pk2(a[0], a[1]);
                    u.y = pk2(a[2], a[3]);
                    *(uint2*)(v_lds + (hl * 32 + e * 16 + ln) * SV + (nt * 16 + hi4 * 4) * 2) = u;
                }
            }
        }
    };

    // ---- attention: 12 units (3 heads x 4 i-tiles) / 4 waves ----
    // P stored UNNORMALIZED (<=1.0); 1/sum folded into o after PV (lane-uniform rinv)
    auto attn = [&](int g) {
        #pragma unroll
        for (int uu = 0; uu < 3; ++uu) {
            const int u = wid + uu * 4;
            const int hl = u >> 2, i0 = (u & 3) * 16;
            const short8 bq = *(const short8*)(q_lds + (i0 + ln) * SQ + hl * 64 + hi4 * 16);
            f32x4 s[4];
            #pragma unroll
            for (int kt = 0; kt < 4; ++kt) {
                const short8 ak = *(const short8*)(k_lds + (kt * 16 + ln) * SQ + hl * 64 + hi4 * 16);
                f32x4 z = {0.f, 0.f, 0.f, 0.f};
                s[kt] = __builtin_amdgcn_mfma_f32_16x16x32_bf16(ak, bq, z, 0, 0, 0);
            }
            // lane (ln, h=hi4) holds S[k = kt*16+h*4+r][i = i0+ln]: 16 vals of row i
            float m = s[0][0];
            #pragma unroll
            for (int kt = 0; kt < 4; ++kt)
                #pragma unroll
                for (int r = 0; r < 4; ++r) m = fmaxf(m, s[kt][r]);
            m = fmaxf(m, __shfl_xor(m, 16));
            m = fmaxf(m, __shfl_xor(m, 32));
            float sum = 0.f;
            #pragma unroll
            for (int kt = 0; kt < 4; ++kt)
                #pragma unroll
                for (int r = 0; r < 4; ++r) {
                    s[kt][r] = EXP2F((s[kt][r] - m) * SC2);
                    sum += s[kt][r];
                }
            sum += __shfl_xor(sum, 16);
            sum += __shfl_xor(sum, 32);
            const float rinv = RCPF(sum);
            // packed unnormalized P store: row i-local = ln, cols j = kt*16+hi4*4+0..3
            #pragma unroll
            for (int kt = 0; kt < 4; ++kt) {
                uint2 u2;
                u2.x = pk2(s[kt][0], s[kt][1]);
                u2.y = pk2(s[kt][2], s[kt][3]);
                *(uint2*)(p_scr + ln * SV + kt * 32 + hi4 * 8) = u2;
            }
            // PV swapped: D[d][i] = vT P^T ; B-frag = P rows i (same-wave read, lgkm only)
            short8 pf[2];
            #pragma unroll
            for (int kc = 0; kc < 2; ++kc)
                pf[kc] = *(const short8*)(p_scr + ln * SV + kc * 64 + hi4 * 16);
            #pragma unroll
            for (int dt = 0; dt < 2; ++dt) {
                f32x4 o = {0.f, 0.f, 0.f, 0.f};
                #pragma unroll
                for (int kc = 0; kc < 2; ++kc) {
                    const short8 av = *(const short8*)(v_lds + (hl * 32 + dt * 16 + ln) * SV + kc * 64 + hi4 * 16);
                    o = __builtin_amdgcn_mfma_f32_16x16x32_bf16(av, pf[kc], o, 0, 0, 0);
                }
                uint2 u2;
                u2.x = pk2(o[0] * rinv, o[1] * rinv);
                u2.y = pk2(o[2] * rinv, o[3] * rinv);
                *(uint2*)(o_lds + (i0 + ln) * SQ + hl * 64 + (dt * 16 + hi4 * 4) * 2) = u2;
            }
        }
    };

    // ---- head-proj partial for group g: acc[c][t] += whc[c][g*96..] * o[t][..] ----
    auto proj = [&](int g) {
        short8 bo[4][3];
        #pragma unroll
        for (int nt = 0; nt < 4; ++nt)
            #pragma unroll
            for (int kt = 0; kt < 3; ++kt)
                bo[nt][kt] = *(const short8*)(o_lds + (nt * 16 + ln) * SQ + kt * 64 + hi4 * 16);
        #pragma unroll
        for (int mm = 0; mm < 3; ++mm) {
            const int c0 = (wid * 3 + mm) * 16;
            short8 af[3];
            #pragma unroll
            for (int kt = 0; kt < 3; ++kt)
                af[kt] = *(const short8*)(whc + (c0 + ln) * 192 + g * 96 + kt * 32 + hi4 * 8);
            #pragma unroll
            for (int nt = 0; nt < 4; ++nt)
                #pragma unroll
                for (int kt = 0; kt < 3; ++kt)
                    acc[mm][nt] = __builtin_amdgcn_mfma_f32_16x16x32_bf16(af[kt], bo[nt][kt], acc[mm][nt], 0, 0, 0);
        }
    };

    qkv(0);
    __syncthreads();
    attn(0);
    __syncthreads();
    proj(0);
    qkv(1);          // fused with proj(0): disjoint buffers, no barrier needed
    __syncthreads();
    attn(1);
    __syncthreads();
    proj(1);

    // ---- final store: out[c][spatial t] = acc + head_b ----
    #pragma unroll
    for (int mm = 0; mm < 3; ++mm) {
        const int c0 = (wid * 3 + mm) * 16;
        const float4 hb = *(const float4*)(head_b + c0 + hi4 * 4);
        #pragma unroll
        for (int nt = 0; nt < 4; ++nt) {
            const int tt = nt * 16 + ln;
            const int y = tt >> 3, xx = tt & 7;
            float* op = out + ((size_t)(b * 192) * 384 + (row0 + y)) * 384 + (col0 + xx);
            op[(size_t)(c0 + hi4 * 4 + 0) * 147456] = acc[mm][nt][0] + hb.x;
            op[(size_t)(c0 + hi4 * 4 + 1) * 147456] = acc[mm][nt][1] + hb.y;
            op[(size_t)(c0 + hi4 * 4 + 2) * 147456] = acc[mm][nt][2] + hb.z;
            op[(size_t)(c0 + hi4 * 4 + 3) * 147456] = acc[mm][nt][3] + hb.w;
        }
    }
}

extern "C" void kernel_launch(void* const* d_in, const int* in_sizes, int n_in,
                              void* d_out, int out_size, void* d_ws, size_t ws_size,
                              hipStream_t stream) {
    const float* x      = (const float*)d_in[0];
    const float* qkv_w  = (const float*)d_in[1];
    const float* qkv_b  = (const float*)d_in[2];
    const float* head_w = (const float*)d_in[3];
    const float* head_b = (const float*)d_in[4];
    float* out = (float*)d_out;

    unsigned short* wq  = (unsigned short*)d_ws;   // 576*192 ushort
    unsigned short* whc = wq + 576 * 192;          // 192*192 ushort

    cvt_weights<<<432, 256, 0, stream>>>(qkv_w, head_w, wq, whc);

    hipFuncSetAttribute((const void*)wmha, hipFuncAttributeMaxDynamicSharedMemorySize, LDS_TOTAL);
    wmha<<<9216, 256, LDS_TOTAL, stream>>>(x, qkv_b, head_b, wq, whc, out);
}